// Round 10
// baseline (337.351 us; speedup 1.0000x reference)
//
#include <hip/hip_runtime.h>
#include <stdint.h>

// ---------------------------------------------------------------------------
// NIVR: coord-MLP over 512x512 grid.
//   pre_kernel: posenc tables, time branch folded -> Txp (=Tx+tvec), Ty;
//               W2f -> bf16 frag-swizzled W2s.
//   main: h1 = relu(Txp[x]+Ty[y]); layer2 via MFMA bf16 16x16x32;
//         fused layer3 epilogue via shuffles. Output [3][N].
//
// R10 vs R9: five structures all ~232-243us, MfmaUtil ~25%, across different
// occupancy/tiles/staging => hypothesis: PIPE PHASE-LOCKING. All waves run
// the same phase simultaneously (VMEM burst -> DS burst -> MFMA burst), so
// TA/DS/matrix pipes serialize (~1500cyc/step vs 620 overlapped).
//  - Per-wave K-rotation: wave w starts its K-loop at step (2w)&15 and wraps
//    (K-order free: acc is a sum; A fully LDS-resident). 8 waves spread over
//    16 steps; the 2 waves/SIMD are offset by 8 steps. Pipes overlap.
//  - A-fill back to R5's conflict-free slot map (R9 had 6.29M conflict cyc).
//  - Keeps R9's depth-2 B / depth-1 A register pipelines, rotated.
// ---------------------------------------------------------------------------

typedef short bf16x8 __attribute__((ext_vector_type(8)));
typedef float f32x4 __attribute__((ext_vector_type(4)));

#define PI_F 3.14159265358979323846f
#define SIDE 512
#define NPIX (SIDE * SIDE)

__device__ __forceinline__ unsigned short f2bf(float f) {
  unsigned int u = __float_as_uint(f);
  u += 0x7fffu + ((u >> 16) & 1u);
  return (unsigned short)(u >> 16);
}

// ---------------------------------------------------------------------------
// Fused precompute kernel. Grid = 1024 blocks x 512 threads:
//   blocks 0..511  : posenc tables for coord v=b, time branch folded:
//                    Txp[v][k] = tvec[k] + sum_l enc[l] W1f[l][k]
//                    Ty [v][k] =           sum_l enc[l] W1f[20+l][k]
//   blocks 512..1023: W2f -> bf16 frag-swizzled W2s (k-row = b-512)
// W2s layout: id = ks*16384 + nt*512 + q*128 + ni*8 + j  (shorts)
//   W2s[id] = bf16(W2f[ks*32 + q*8 + j][nt*16 + ni])
// ---------------------------------------------------------------------------
__global__ void pre_kernel(const float* __restrict__ W1p, const float* __restrict__ b1p,
                           const float* __restrict__ W2p, const float* __restrict__ b2p,
                           const float* __restrict__ W1f, const float* __restrict__ b1f,
                           const float* __restrict__ W2f, const int* __restrict__ idx,
                           float* __restrict__ Txp, float* __restrict__ Ty,
                           unsigned short* __restrict__ W2s) {
  const int b = blockIdx.x;
  const int t = threadIdx.x;

  if (b >= 512) {
    const int k = b - 512, n = t;
    const int ks = k >> 5, q = (k >> 3) & 3, j = k & 7;
    const int nt = n >> 4, ni = n & 15;
    W2s[ks * 16384 + nt * 512 + q * 128 + ni * 8 + j] = f2bf(W2f[k * 512 + n]);
    return;
  }

  __shared__ float enc[20];
  __shared__ float r_s[32];
  __shared__ float h_s[256];
  __shared__ float phi_s[128];

  if (t < 10) {
    float u = (float)b / 512.0f;
    float ang = u * ldexpf(PI_F, t);
    enc[t] = sinf(ang);
    enc[10 + t] = cosf(ang);
  }
  if (t >= 32 && t < 48) {
    const int l = t - 32;
    float tt = (float)idx[0] / 300.0f;
    float ang = tt * ldexpf(PI_F, l);
    r_s[l] = sinf(ang);
    r_s[16 + l] = cosf(ang);
  }
  __syncthreads();
  if (t < 256) {
    float a = b1p[t];
#pragma unroll
    for (int i = 0; i < 32; ++i) a += r_s[i] * W1p[i * 256 + t];
    h_s[t] = fmaxf(a, 0.f);
  }
  __syncthreads();
  if (t < 128) {
    float a = b2p[t];
    for (int i = 0; i < 256; ++i) a += h_s[i] * W2p[i * 128 + t];
    phi_s[t] = a;
  }
  __syncthreads();
  {
    float tv = b1f[t];
    for (int p = 0; p < 128; ++p) tv += phi_s[p] * W1f[(40 + p) * 512 + t];
    float ax = tv, ay = 0.f;
#pragma unroll
    for (int l = 0; l < 20; ++l) {
      ax += enc[l] * W1f[l * 512 + t];
      ay += enc[l] * W1f[(20 + l) * 512 + t];
    }
    Txp[b * 512 + t] = ax;
    Ty[b * 512 + t] = ay;
  }
}

// ---------------------------------------------------------------------------
// Main fused kernel. Block = 512 thr (8 waves), BM=64 (8x8 patch), BN=512,
// K=512 in 16 steps of 32, per-wave rotated start. Wave w owns N-slice
// [w*64, w*64+64). A tile 64KB resident in LDS; B depth-2 register pipeline.
// ---------------------------------------------------------------------------
__global__ __launch_bounds__(512, 2) void main_kernel(
    const float* __restrict__ Txp, const float* __restrict__ Ty,
    const unsigned short* __restrict__ W2s, const float* __restrict__ b2f,
    const float* __restrict__ W3f, const float* __restrict__ b3f,
    float* __restrict__ out) {
  __shared__ __attribute__((aligned(16))) unsigned short Ab[16 * 2048];  // 64KB
  __shared__ float part[8][64][3];                                       // 6KB

  const int t = threadIdx.x;
  const int w = t >> 6;            // wave id 0..7  (N-slice)
  const int lane = t & 63;
  const int q = lane >> 4;
  const int lr = lane & 15;
  const int x0 = blockIdx.x * 8, y0 = blockIdx.y * 8;

  // B: wave w owns nt-slots w*4..w*4+3; frag (ks,nt) at +ks*16384 + nt*512;
  // lane reads at +lane*8 (16B, coalesced 1KB/wave).
  const unsigned short* bptr = W2s + (w * 4) * 512 + lane * 8;

  // per-wave K rotation: wave w starts at step (2w)&15, wraps mod 16.
  const int kbase = (2 * w) & 15;

  // ---- B pipeline prologue: steps kbase, kbase+1 ----
  bf16x8 breg[3][4];
#pragma unroll
  for (int nt = 0; nt < 4; ++nt) {
    breg[0][nt] = *(const bf16x8*)(bptr + kbase * 16384 + nt * 512);
    breg[1][nt] = *(const bf16x8*)(bptr + (((kbase + 1) & 15) * 16384) + nt * 512);
  }

  // ---- A fill (once), conflict-free slot map (R5-verified): thread owns
  // slot v=t&255 -> (mt=v>>6, q2=(v>>4)&3, mr=v&15), pixel p=mt*16+mr;
  // group g=t>>8 covers slabs ks = g+2i; one uint4 write at v*16B per slab.
  {
    const int v = t & 255, g = t >> 8;
    const int p = ((v >> 6) << 4) + (v & 15);
    const int q2 = (v >> 4) & 3;
    const int xi = x0 + (p >> 3), yi = y0 + (p & 7);
    const float* txp = Txp + xi * 512 + q2 * 8;
    const float* typ = Ty + yi * 512 + q2 * 8;
#pragma unroll
    for (int i = 0; i < 8; ++i) {
      const int ks = g + 2 * i;
      const int ko = ks * 32;
      float4 a0 = *(const float4*)(txp + ko);
      float4 a1 = *(const float4*)(txp + ko + 4);
      float4 b0 = *(const float4*)(typ + ko);
      float4 b1 = *(const float4*)(typ + ko + 4);
      uint4 pk;
      pk.x = (unsigned)f2bf(fmaxf(a0.x + b0.x, 0.f)) |
             ((unsigned)f2bf(fmaxf(a0.y + b0.y, 0.f)) << 16);
      pk.y = (unsigned)f2bf(fmaxf(a0.z + b0.z, 0.f)) |
             ((unsigned)f2bf(fmaxf(a0.w + b0.w, 0.f)) << 16);
      pk.z = (unsigned)f2bf(fmaxf(a1.x + b1.x, 0.f)) |
             ((unsigned)f2bf(fmaxf(a1.y + b1.y, 0.f)) << 16);
      pk.w = (unsigned)f2bf(fmaxf(a1.z + b1.z, 0.f)) |
             ((unsigned)f2bf(fmaxf(a1.w + b1.w, 0.f)) << 16);
      *(uint4*)&Ab[ks * 2048 + v * 8] = pk;
    }
  }

  f32x4 acc[4][4];
#pragma unroll
  for (int i = 0; i < 4; ++i)
#pragma unroll
    for (int j2 = 0; j2 < 4; ++j2) acc[i][j2] = (f32x4){0.f, 0.f, 0.f, 0.f};

  __syncthreads();  // publishes A; the only barrier before the epilogue

  // ---- A-frag pipeline prologue: step kbase ----
  bf16x8 areg[2][4];
#pragma unroll
  for (int mt = 0; mt < 4; ++mt)
    areg[0][mt] = *(const bf16x8*)&Ab[kbase * 2048 + mt * 512 + lane * 8];

  // ---- K-loop, rotated per wave, fully unrolled, no barriers ----
#pragma unroll
  for (int kk = 0; kk < 16; ++kk) {
    if (kk + 2 < 16) {
      const int ks2 = (kbase + kk + 2) & 15;
#pragma unroll
      for (int nt = 0; nt < 4; ++nt)
        breg[(kk + 2) % 3][nt] =
            *(const bf16x8*)(bptr + ks2 * 16384 + nt * 512);
    }
    if (kk + 1 < 16) {
      const int ks1 = (kbase + kk + 1) & 15;
#pragma unroll
      for (int mt = 0; mt < 4; ++mt)
        areg[(kk + 1) & 1][mt] =
            *(const bf16x8*)&Ab[ks1 * 2048 + mt * 512 + lane * 8];
    }
#pragma unroll
    for (int nt = 0; nt < 4; ++nt)
#pragma unroll
      for (int mt = 0; mt < 4; ++mt)
        acc[mt][nt] = __builtin_amdgcn_mfma_f32_16x16x32_bf16(
            areg[kk & 1][mt], breg[kk % 3][nt], acc[mt][nt], 0, 0, 0);
  }

  // ---- epilogue: h2 = relu(acc + b2f); rgb partial = h2 @ W3f (k-slice) ----
  float w3v[4][3];
  float bb2[4];
#pragma unroll
  for (int nt = 0; nt < 4; ++nt) {
    const int k = w * 64 + nt * 16 + lr;
    bb2[nt] = b2f[k];
    w3v[nt][0] = W3f[k * 3 + 0];
    w3v[nt][1] = W3f[k * 3 + 1];
    w3v[nt][2] = W3f[k * 3 + 2];
  }
#pragma unroll
  for (int half = 0; half < 2; ++half) {
    float vv[2][4][3];
#pragma unroll
    for (int mi = 0; mi < 2; ++mi)
#pragma unroll
      for (int r = 0; r < 4; ++r)
#pragma unroll
        for (int cc = 0; cc < 3; ++cc) vv[mi][r][cc] = 0.f;
#pragma unroll
    for (int mi = 0; mi < 2; ++mi) {
      const int mt = half * 2 + mi;
#pragma unroll
      for (int r = 0; r < 4; ++r) {
#pragma unroll
        for (int nt = 0; nt < 4; ++nt) {
          float h2 = fmaxf(acc[mt][nt][r] + bb2[nt], 0.f);
          vv[mi][r][0] += h2 * w3v[nt][0];
          vv[mi][r][1] += h2 * w3v[nt][1];
          vv[mi][r][2] += h2 * w3v[nt][2];
        }
      }
    }
#pragma unroll
    for (int d = 1; d < 16; d <<= 1) {
#pragma unroll
      for (int mi = 0; mi < 2; ++mi)
#pragma unroll
        for (int r = 0; r < 4; ++r)
#pragma unroll
          for (int cc = 0; cc < 3; ++cc)
            vv[mi][r][cc] += __shfl_xor(vv[mi][r][cc], d, 64);
    }
    if (lr == 0) {
#pragma unroll
      for (int mi = 0; mi < 2; ++mi)
#pragma unroll
        for (int r = 0; r < 4; ++r) {
          const int row = (half * 2 + mi) * 16 + q * 4 + r;
#pragma unroll
          for (int cc = 0; cc < 3; ++cc) part[w][row][cc] = vv[mi][r][cc];
        }
    }
  }
  __syncthreads();
  if (t < 192) {
    const int c = t >> 6, mm = t & 63;
    float sum = b3f[c];
#pragma unroll
    for (int ww = 0; ww < 8; ++ww) sum += part[ww][mm][c];
    const int n = (x0 + (mm >> 3)) * 512 + (y0 + (mm & 7));
    out[c * NPIX + n] = sum;
  }
}

// ---------------------------------------------------------------------------
// Inputs: 0 coords (unused), 1 W1p, 2 b1p, 3 W2p, 4 b2p, 5 W1f, 6 b1f,
//         7 W2f, 8 b2f, 9 W3f, 10 b3f, 11 idx
// ---------------------------------------------------------------------------
extern "C" void kernel_launch(void* const* d_in, const int* in_sizes, int n_in,
                              void* d_out, int out_size, void* d_ws, size_t ws_size,
                              hipStream_t stream) {
  const float* W1p = (const float*)d_in[1];
  const float* b1p = (const float*)d_in[2];
  const float* W2p = (const float*)d_in[3];
  const float* b2p = (const float*)d_in[4];
  const float* W1f = (const float*)d_in[5];
  const float* b1f = (const float*)d_in[6];
  const float* W2f = (const float*)d_in[7];
  const float* b2f = (const float*)d_in[8];
  const float* W3f = (const float*)d_in[9];
  const float* b3f = (const float*)d_in[10];
  const int* idx = (const int*)d_in[11];
  float* out = (float*)d_out;

  char* ws = (char*)d_ws;
  float* Txp = (float*)ws;                                   // 1 MB
  float* Ty = (float*)(ws + (1u << 20));                     // 1 MB
  unsigned short* W2s = (unsigned short*)(ws + (2u << 20));  // 512 KB

  hipLaunchKernelGGL(pre_kernel, dim3(1024), dim3(512), 0, stream,
                     W1p, b1p, W2p, b2p, W1f, b1f, W2f, idx, Txp, Ty, W2s);
  hipLaunchKernelGGL(main_kernel, dim3(64, 64), dim3(512), 0, stream,
                     Txp, Ty, W2s, b2f, W3f, b3f, out);
}